// Round 12
// baseline (1274.525 us; speedup 1.0000x reference)
//
#include <hip/hip_runtime.h>
#include <cstdint>
#include <cstddef>

// ---------------- problem constants ----------------
#define BB   4      // batch
#define CIN  64     // input channels
#define HD   128    // h_dim
#define NH   4      // heads
#define CHW  32     // channels per head
#define CB   8      // channels per branch
#define IMG  192    // H = W
#define SSH  4      // shift
#define NWS  24     // windows per side
#define NWIN 576    // windows total
#define KK   64     // window elements (8x8)
#define HWP  (IMG*IMG)

// per-batch buffer sizes (floats)
static const size_t NQK16  = (size_t)NH*NWIN*KK*16;   // 2,359,296
static const size_t NV32   = (size_t)NH*NWIN*KK*CHW;  // 4,718,592
static const size_t NGR    = (size_t)NH*KK*NWIN*CB;   // 1,179,648
static const size_t NSP    = (size_t)HD*HWP;          // 4,718,592
static const size_t NATTNB = (size_t)NH*NWIN*KK*KK;   // 9,437,184
static const size_t NATTNL = (size_t)NH*NWIN*64;      // 147,456
static const size_t NATTNG = (size_t)NH*KK*64;        // 16,384
static const size_t NATTNR = (size_t)NH*CB*KK*KK;     // 131,072
static const size_t NPART  = (size_t)8*NATTNR;        // 1,048,576

// ---------------- helpers ----------------
__device__ inline float wave_max(float v){
  #pragma unroll
  for (int s=1;s<64;s<<=1) v = fmaxf(v, __shfl_xor(v, s));
  return v;
}
__device__ inline float wave_sum(float v){
  #pragma unroll
  for (int s=1;s<64;s<<=1) v += __shfl_xor(v, s);
  return v;
}
__device__ inline float g8_max(float v){
  v = fmaxf(v, __shfl_xor(v,1)); v = fmaxf(v, __shfl_xor(v,2)); v = fmaxf(v, __shfl_xor(v,4));
  return v;
}
__device__ inline float g8_sum(float v){
  v += __shfl_xor(v,1); v += __shfl_xor(v,2); v += __shfl_xor(v,4);
  return v;
}
__device__ inline int regionc(int y){ return (y < IMG-8) ? 0 : ((y < IMG-4) ? 1 : 2); }

__device__ inline size_t widx(int h,int n,int i,int c){
  return (((size_t)h*NWIN + n)*KK + i)*CHW + c;
}
__device__ inline size_t widx16(int h,int n,int i,int c){
  return (((size_t)h*NWIN + n)*KK + i)*16 + c;
}
__device__ inline size_t gidx(int h,int i,int n,int c){
  return (((size_t)(h*KK + i))*NWIN + n)*CB + c;
}
__device__ inline size_t ridx(int h,int c,int n,int i){
  return (((size_t)(h*CB + c))*NWIN + n)*KK + i;
}

// ---------------- K1: projections (wave-coherent stores + LDS-transposed u/z) ----------------
__global__ __launch_bounds__(256) void k1_proj(
    const float* __restrict__ x, const float* __restrict__ wquz, const float* __restrict__ wkv,
    float* __restrict__ qw, float* __restrict__ kw, float* __restrict__ vw,
    float* __restrict__ qg, float* __restrict__ kg,
    float* __restrict__ qr, float* __restrict__ kr,
    float* __restrict__ u, float* __restrict__ zbuf, int bsel)
{
  __shared__ float xs[64][20];
  __shared__ float tb[128][17];   // transpose buffer for u / z spatial stores
  int blk = blockIdx.x;
  int xc = blk % 12, y = blk / 12;
  int x0 = xc*16;
  int t = threadIdx.x;
  {
    int c = t >> 2, p4 = (t & 3)*4;
    float4 v = *(const float4*)&x[((size_t)(bsel*CIN+c)*IMG + y)*IMG + x0 + p4];
    *(float4*)&xs[c][p4] = v;
  }
  int py  = (y + IMG - SSH) % IMG;
  int kh  = py & 7, hwq = py >> 3;
  int wwA = ((x0 - SSH + IMG) % IMG) >> 3;
  int wwB = x0 >> 3;
  int wwC = (x0 + 8) >> 3;
  int pnA = hwq*NWS + wwA, pnB = hwq*NWS + wwB, pnC = hwq*NWS + wwC;
  int piA = kh*8 + 4, piB = kh*8, piC = kh*8;
  #define PN_(p) ((p)<4 ? pnA : ((p)<12 ? pnB : pnC))
  #define PI_(p) ((p)<4 ? (piA+(p)) : ((p)<12 ? (piB+(p)-4) : (piC+(p)-12)))
  __syncthreads();

  int o;
  if (t < 64)       o = (t>>4)*32 + (t&15);
  else if (t < 96)  o = ((t-64)>>3)*32 + 16 + (t&7);
  else if (t < 128) o = ((t-96)>>3)*32 + 24 + (t&7);
  else              o = t;

  // ---- pass 0: q (waves 0-1) / u -> LDS (waves 2-3) ----
  {
    const float* wr = wquz + (size_t)o*CIN;
    float acc[16];
    #pragma unroll
    for (int p = 0; p < 16; ++p) acc[p] = 0.f;
    for (int cc = 0; cc < 64; cc += 4){
      float4 w4 = *(const float4*)(wr + cc);
      #pragma unroll
      for (int p = 0; p < 16; ++p){
        acc[p] += w4.x * xs[cc  ][p];
        acc[p] += w4.y * xs[cc+1][p];
        acc[p] += w4.z * xs[cc+2][p];
        acc[p] += w4.w * xs[cc+3][p];
      }
    }
    if (t < 64){
      int h = t >> 4, c = t & 15;
      #pragma unroll
      for (int p = 0; p < 16; ++p) qw[widx16(h,PN_(p),PI_(p),c)] = acc[p];
    } else if (t < 96){
      int h = (t-64) >> 3, cg = t & 7;
      #pragma unroll
      for (int p = 0; p < 16; ++p) qg[gidx(h,PI_(p),PN_(p),cg)] = acc[p];
    } else if (t < 128){
      int h = (t-96) >> 3, cr = t & 7;
      *(float4*)&qr[ridx(h,cr,pnA,piA)]   = make_float4(acc[0],acc[1],acc[2],acc[3]);
      *(float4*)&qr[ridx(h,cr,pnB,piB)]   = make_float4(acc[4],acc[5],acc[6],acc[7]);
      *(float4*)&qr[ridx(h,cr,pnB,piB+4)] = make_float4(acc[8],acc[9],acc[10],acc[11]);
      *(float4*)&qr[ridx(h,cr,pnC,piC)]   = make_float4(acc[12],acc[13],acc[14],acc[15]);
    } else {
      int ch = o - 128;
      #pragma unroll
      for (int p = 0; p < 16; ++p) tb[ch][p] = acc[p];
    }
  }
  __syncthreads();
  // transposed u store: lane = pixel, 4x64B segments/inst
  {
    int px = t & 15, chg = t >> 4;
    size_t ub = (size_t)y*IMG + x0 + px;
    #pragma unroll
    for (int cc = 0; cc < 8; ++cc){
      int ch = chg*8 + cc;
      u[(size_t)ch*HWP + ub] = tb[ch][px];
    }
  }

  // ---- pass 1: k (waves 0-1) / v (waves 2-3) ----
  {
    const float* wr = wkv + (size_t)o*CIN;
    float acc[16];
    #pragma unroll
    for (int p = 0; p < 16; ++p) acc[p] = 0.f;
    for (int cc = 0; cc < 64; cc += 4){
      float4 w4 = *(const float4*)(wr + cc);
      #pragma unroll
      for (int p = 0; p < 16; ++p){
        acc[p] += w4.x * xs[cc  ][p];
        acc[p] += w4.y * xs[cc+1][p];
        acc[p] += w4.z * xs[cc+2][p];
        acc[p] += w4.w * xs[cc+3][p];
      }
    }
    if (t < 64){
      int h = t >> 4, c = t & 15;
      #pragma unroll
      for (int p = 0; p < 16; ++p) kw[widx16(h,PN_(p),PI_(p),c)] = acc[p];
    } else if (t < 96){
      int h = (t-64) >> 3, cg = t & 7;
      #pragma unroll
      for (int p = 0; p < 16; ++p) kg[gidx(h,PI_(p),PN_(p),cg)] = acc[p];
    } else if (t < 128){
      int h = (t-96) >> 3, cr = t & 7;
      *(float4*)&kr[ridx(h,cr,pnA,piA)]   = make_float4(acc[0],acc[1],acc[2],acc[3]);
      *(float4*)&kr[ridx(h,cr,pnB,piB)]   = make_float4(acc[4],acc[5],acc[6],acc[7]);
      *(float4*)&kr[ridx(h,cr,pnB,piB+4)] = make_float4(acc[8],acc[9],acc[10],acc[11]);
      *(float4*)&kr[ridx(h,cr,pnC,piC)]   = make_float4(acc[12],acc[13],acc[14],acc[15]);
    } else {
      int oc = o - 128; int h = oc >> 5, c = oc & 31;
      #pragma unroll
      for (int p = 0; p < 16; ++p) vw[widx(h,PN_(p),PI_(p),c)] = acc[p];
    }
  }

  // ---- pass 2: z -> LDS -> transposed store ----
  __syncthreads();   // all u-store LDS reads done before overwriting tb
  {
    int zr = t >> 1, ph = t & 1;
    const float* wr = wquz + (size_t)(256 + zr)*CIN;
    int pb = ph*8;
    float acc[8];
    #pragma unroll
    for (int p = 0; p < 8; ++p) acc[p] = 0.f;
    for (int cc = 0; cc < 64; cc += 4){
      float4 w4 = *(const float4*)(wr + cc);
      #pragma unroll
      for (int p = 0; p < 8; ++p){
        acc[p] += w4.x * xs[cc  ][pb+p];
        acc[p] += w4.y * xs[cc+1][pb+p];
        acc[p] += w4.z * xs[cc+2][pb+p];
        acc[p] += w4.w * xs[cc+3][pb+p];
      }
    }
    #pragma unroll
    for (int p = 0; p < 8; ++p) tb[zr][pb+p] = acc[p];
  }
  __syncthreads();
  {
    int px = t & 15, chg = t >> 4;
    size_t zb = (size_t)y*IMG + x0 + px;
    #pragma unroll
    for (int cc = 0; cc < 8; ++cc){
      int ch = chg*8 + cc;
      zbuf[(size_t)ch*HWP + zb] = tb[ch][px];
    }
  }
  #undef PN_
  #undef PI_
}

// ---------------- kA umbrella: k3 | k5a | k6a(+g-norm) | k7a | kNr ----------------
__global__ __launch_bounds__(256) void kA(
    const float* __restrict__ qw, const float* __restrict__ kw,
    const float* __restrict__ qg, const float* __restrict__ kg,
    const float* __restrict__ qr, const float* __restrict__ kr,
    const float* __restrict__ temp,
    float* __restrict__ attnB, float* __restrict__ attnL,
    float* __restrict__ attnG, float* __restrict__ part,
    float* __restrict__ invqr, float* __restrict__ invkr)
{
  __shared__ __align__(16) char smem[36864];
  int blk = blockIdx.x;
  int t = threadIdx.x;

  if (blk < 576){
    float (*qs)[64][8] = (float(*)[64][8])smem;
    int wv = t >> 6, j = t & 63;
    int gid = blk*4 + wv;
    int n = gid % NWIN, h = gid / NWIN;
    size_t base = widx16(h,n,j,0);
    float q8[CB], k8[CB];
    float sq = 0.f, sk2 = 0.f;
    #pragma unroll
    for (int c = 0; c < CB; ++c){
      q8[c] = qw[base+c]; sq += q8[c]*q8[c];
      k8[c] = kw[base+c]; sk2 += k8[c]*k8[c];
    }
    float invq = 1.f/fmaxf(sqrtf(sq),1e-12f), invk = 1.f/fmaxf(sqrtf(sk2),1e-12f);
    #pragma unroll
    for (int c = 0; c < CB; ++c){ qs[wv][j][c] = q8[c]*invq; k8[c] *= invk; }
    __syncthreads();
    float tmp = temp[h];
    float* orow = attnB + (size_t)gid*KK*KK;
    for (int i = 0; i < KK; ++i){
      float a = 0.f;
      #pragma unroll
      for (int c = 0; c < CB; ++c) a += qs[wv][i][c]*k8[c];
      orow[(size_t)i*KK + j] = a * tmp;
    }
  } else if (blk < 1152){
    int b2 = blk - 576;
    float (*qs)[64][8] = (float(*)[64][8])smem;
    float (*ks)[64][8] = (float(*)[64][8])(smem + 8192);
    float (*invqA)[8] = (float(*)[8])(smem + 16384);
    float (*invkA)[8] = (float(*)[8])(smem + 16384 + 128);
    int wv = t >> 6, tl = t & 63;
    int gid = b2*4 + wv;
    int n = gid % NWIN, h = gid / NWIN;
    size_t base = widx16(h,n,tl,8);
    #pragma unroll
    for (int c = 0; c < CB; ++c){ qs[wv][tl][c] = qw[base+c]; ks[wv][tl][c] = kw[base+c]; }
    __syncthreads();
    int c8 = tl & 7, ig = tl >> 3;
    float sq = 0.f, sk2 = 0.f;
    for (int i = ig; i < KK; i += 8){
      float a = qs[wv][i][c8]; sq += a*a;
      float b = ks[wv][i][c8]; sk2 += b*b;
    }
    #pragma unroll
    for (int m = 8; m < 64; m <<= 1){ sq += __shfl_xor(sq,m); sk2 += __shfl_xor(sk2,m); }
    if (tl < 8){ invqA[wv][tl] = 1.f/fmaxf(sqrtf(sq),1e-12f); invkA[wv][tl] = 1.f/fmaxf(sqrtf(sk2),1e-12f); }
    __syncthreads();
    int c = tl >> 3, d = tl & 7;
    float a = 0.f;
    for (int i = 0; i < KK; ++i) a += qs[wv][i][c]*ks[wv][i][d];
    attnL[(size_t)gid*64 + tl] = a * invqA[wv][c] * invkA[wv][d] * temp[NH + h];
  } else if (blk < 1408){
    int b2 = blk - 1152;
    int i = b2 & 63, h = b2 >> 6;
    float* sq = (float*)smem;
    float* sk = sq + 512;
    float (*redA)[64] = (float(*)[64])(smem + 4096);
    float (*redQ)[64] = (float(*)[64])(smem + 4096 + 1024);
    float (*redK)[64] = (float(*)[64])(smem + 4096 + 2048);
    size_t base = ((size_t)(h*KK+i))*NWIN*CB;
    int np = t >> 6, cd = t & 63, c = cd >> 3, d = cd & 7;
    float a = 0.f, qs2 = 0.f, ks2 = 0.f;
    for (int n0 = 0; n0 < NWIN; n0 += 64){
      __syncthreads();
      for (int idx = t; idx < 512; idx += 256){
        sq[idx] = qg[base + (size_t)n0*CB + idx];
        sk[idx] = kg[base + (size_t)n0*CB + idx];
      }
      __syncthreads();
      for (int nn = np; nn < 64; nn += 4){
        float qv = sq[nn*8+c], kv = sk[nn*8+d];
        a += qv*kv; qs2 += qv*qv; ks2 += kv*kv;
      }
    }
    __syncthreads();
    redA[np][cd] = a; redQ[np][cd] = qs2; redK[np][cd] = ks2;
    __syncthreads();
    if (t < 64){
      float at = redA[0][t]+redA[1][t]+redA[2][t]+redA[3][t];
      float qt = redQ[0][t]+redQ[1][t]+redQ[2][t]+redQ[3][t];
      float kt = redK[0][t]+redK[1][t]+redK[2][t]+redK[3][t];
      at *= (1.f/fmaxf(sqrtf(qt),1e-12f)) * (1.f/fmaxf(sqrtf(kt),1e-12f)) * temp[2*NH + h];
      attnG[(size_t)(h*KK+i)*64 + t] = at;
    }
  } else if (blk < 1664){
    int b2 = blk - 1408;
    int chunk = b2 >> 5, hc = b2 & 31;
    int n0 = chunk*72;
    float* sq = (float*)smem;
    float* sk = sq + 72*64;
    size_t base = (size_t)hc*NWIN*KK + (size_t)n0*KK;
    for (int idx = t; idx < 72*64/4; idx += 256){
      *(float4*)&sq[idx*4] = *(const float4*)&qr[base + (size_t)idx*4];
      *(float4*)&sk[idx*4] = *(const float4*)&kr[base + (size_t)idx*4];
    }
    __syncthreads();
    int j = t & 63, ig = t >> 6;
    float acc[16];
    #pragma unroll
    for (int p = 0; p < 16; ++p) acc[p] = 0.f;
    for (int nn = 0; nn < 72; ++nn){
      float kv = sk[nn*64+j];
      #pragma unroll
      for (int p = 0; p < 16; ++p) acc[p] += sq[nn*64 + ig*16 + p]*kv;
    }
    float* ob = part + (size_t)b2*4096;
    #pragma unroll
    for (int p = 0; p < 16; ++p) ob[(size_t)(ig*16+p)*64 + j] = acc[p];
  } else {
    int hc = blk - 1664;
    float (*rq)[64] = (float(*)[64])smem;
    float (*rk)[64] = (float(*)[64])(smem + 1024);
    size_t base = (size_t)hc*NWIN*KK;
    int i = t & 63, ng = t >> 6;
    float sq = 0.f, sk2 = 0.f;
    for (int n = ng; n < NWIN; n += 4){
      float a = qr[base + (size_t)n*KK + i]; sq  += a*a;
      float b = kr[base + (size_t)n*KK + i]; sk2 += b*b;
    }
    rq[ng][i] = sq; rk[ng][i] = sk2;
    __syncthreads();
    if (t < 64){
      float s = rq[0][t]+rq[1][t]+rq[2][t]+rq[3][t];
      invqr[hc*KK + t] = 1.f/fmaxf(sqrtf(s),1e-12f);
    } else if (t < 128){
      int i2 = t - 64;
      float s = rk[0][i2]+rk[1][i2]+rk[2][i2]+rk[3][i2];
      invkr[hc*KK + i2] = 1.f/fmaxf(sqrtf(s),1e-12f);
    }
  }
}

// ---------------- kB umbrella: k4(XCD-swizzled) | k5b | k6b | kRed | k_dw ----------------
__global__ __launch_bounds__(256) void kB(
    const float* __restrict__ attnB, const float* __restrict__ btw,
    const float* __restrict__ vw, float* __restrict__ outa,
    const float* __restrict__ attnL, const float* __restrict__ ltw,
    const float* __restrict__ attnG, const float* __restrict__ gtalk,
    float* __restrict__ attnGp,
    const float* __restrict__ part, const float* __restrict__ invqr,
    const float* __restrict__ invkr, const float* __restrict__ temp,
    float* __restrict__ attnR,
    const float* __restrict__ u, const float* __restrict__ dww,
    float* __restrict__ dwu)
{
  __shared__ __align__(16) char smem[12800];
  int blk = blockIdx.x;
  int t = threadIdx.x;

  if (blk < 9216){
    // ---- k4 v3: XCD-aware swizzle (9216 % 8 == 0 -> bijective) ----
    // XCD x executes logical works [x*1152, (x+1)*1152): contiguous n-sweeps
    // whose 9-neighbor attnB slices stay resident in that XCD's private L2.
    int wk = (blk & 7)*1152 + (blk >> 3);
    float (*pbuf)[4][66] = (float(*)[4][66])smem;
    float (*vv)[8][66]   = (float(*)[8][66])(smem + 4224);
    int ig = wk / NWIN, n = wk % NWIN;
    int i0 = ig*4;
    int hw = n / NWS, ww = n % NWS;
    int w = t >> 6, l = t & 63;
    {
      size_t vb = widx(w, n, l, 0);
      float4 va = *(const float4*)&vw[vb];
      float4 vb4 = *(const float4*)&vw[vb + 4];
      vv[w][0][l] = va.x;  vv[w][1][l] = va.y;  vv[w][2][l] = va.z;  vv[w][3][l] = va.w;
      vv[w][4][l] = vb4.x; vv[w][5][l] = vb4.y; vv[w][6][l] = vb4.z; vv[w][7][l] = vb4.w;
    }
    int i = i0 + w;
    float a0 = 0.f, a1 = 0.f, a2 = 0.f, a3 = 0.f;
    #pragma unroll
    for (int nb = 0; nb < 9; ++nb){
      const int dy = nb/3 - 1, dx = nb%3 - 1;
      int hw2 = hw + dy, ww2 = ww + dx;
      if (hw2 >= 0 && hw2 < NWS && ww2 >= 0 && ww2 < NWS){
        int n2 = hw2*NWS + ww2;
        #pragma unroll
        for (int h = 0; h < 4; ++h){
          float r = attnB[((size_t)(h*NWIN + n2)*KK + i)*KK + l];
          a0 += btw[(0*4 + h)*9 + nb] * r;
          a1 += btw[(1*4 + h)*9 + nb] * r;
          a2 += btw[(2*4 + h)*9 + nb] * r;
          a3 += btw[(3*4 + h)*9 + nb] * r;
        }
      }
    }
    int kh = i >> 3, kwd = i & 7;
    int cntI = regionc(hw*8 + kh)*3 + regionc(ww*8 + kwd);
    int cntJ = regionc(hw*8 + (l>>3))*3 + regionc(ww*8 + (l&7));
    float mval = (cntI != cntJ) ? -100.f : 0.f;
    a0 += mval; a1 += mval; a2 += mval; a3 += mval;
    {
      float m0 = wave_max(a0); float e0 = __expf(a0 - m0); pbuf[0][w][l] = e0 / wave_sum(e0);
      float m1 = wave_max(a1); float e1 = __expf(a1 - m1); pbuf[1][w][l] = e1 / wave_sum(e1);
      float m2 = wave_max(a2); float e2 = __expf(a2 - m2); pbuf[2][w][l] = e2 / wave_sum(e2);
      float m3 = wave_max(a3); float e3 = __expf(a3 - m3); pbuf[3][w][l] = e3 / wave_sum(e3);
    }
    __syncthreads();
    {
      int i2 = l >> 4, c = (l >> 1) & 7, jq = l & 1;
      const float* pr = &pbuf[w][i2][jq*32];
      const float* vr = &vv[w][c][jq*32];
      float s = 0.f;
      #pragma unroll
      for (int q = 0; q < 32; ++q) s += pr[q] * vr[q];
      s += __shfl_xor(s, 1);
      if (jq == 0){
        int ii = i0 + i2;
        int khh = ii >> 3, kww = ii & 7;
        int Y = (hw*8 + khh + SSH) % IMG;
        int X = (ww*8 + kww + SSH) % IMG;
        outa[((size_t)(w*CB + c)*HWP) + (size_t)Y*IMG + X] = s;
      }
    }
  } else if (blk < 9792){
    // ---- k5b ----
    int n = blk - 9216;
    int hw = n/NWS, ww = n%NWS;
    float (*rows)[9][64] = (float(*)[9][64])smem;
    float* wt = (float*)(smem + 9216);
    float (*P)[8][8] = (float(*)[8][8])(smem + 9792);
    if (t < NH*NH*9) wt[t] = ltw[t];
    for (int l = t; l < NH*9*64; l += 256){
      int h = l/(9*64); int nb = (l/64)%9; int cd = l & 63;
      int dy = nb/3-1, dx = nb%3-1; int hw2 = hw+dy, ww2 = ww+dx;
      float v = 0.f;
      if (hw2>=0 && hw2<NWS && ww2>=0 && ww2<NWS)
        v = attnL[((size_t)h*NWIN + hw2*NWS + ww2)*64 + cd];
      rows[h][nb][cd] = v;
    }
    __syncthreads();
    int tt = t >> 6; int cd = t & 63; int c = cd >> 3, d = cd & 7;
    float a = 0.f;
    #pragma unroll
    for (int h = 0; h < NH; ++h)
      #pragma unroll
      for (int nb = 0; nb < 9; ++nb)
        a += wt[(tt*NH + h)*9 + nb] * rows[h][nb][cd];
    float m = g8_max(a);
    float e = __expf(a - m);
    P[tt][c][d] = e / g8_sum(e);
    __syncthreads();
    int i = t & 63;
    size_t vbase = widx(tt, n, i, 8);
    float vl[CB];
    #pragma unroll
    for (int d2 = 0; d2 < CB; ++d2) vl[d2] = vw[vbase + d2];
    int kh = i>>3, kwd = i&7;
    int Y = (hw*8+kh+SSH)%IMG, X = (ww*8+kwd+SSH)%IMG;
    #pragma unroll
    for (int c2 = 0; c2 < CB; ++c2){
      float o = 0.f;
      #pragma unroll
      for (int d2 = 0; d2 < CB; ++d2) o += P[tt][c2][d2]*vl[d2];
      outa[((size_t)(32 + tt*CB + c2)*IMG + Y)*IMG + X] = o;
    }
  } else if (blk < 9856){
    // ---- k6b ----
    int bb = blk - 9792;
    int w = t >> 6, cd = t & 63;
    int idx = bb*4 + w;
    int l = idx & 63, t2 = idx >> 6;
    float a = 0.f;
    for (int h = 0; h < NH; ++h)
      for (int k = 0; k < KK; ++k)
        a += gtalk[((size_t)(h*KK + k)*KK + l)*NH + t2] * attnG[((size_t)h*KK + k)*64 + cd];
    float m = g8_max(a);
    float e = __expf(a - m);
    attnGp[((size_t)t2*KK + l)*64 + cd] = e / g8_sum(e);
  } else if (blk < 10368){
    // ---- kRed ----
    int e = (blk - 9856)*256 + t;
    float s = 0.f;
    #pragma unroll
    for (int ch = 0; ch < 8; ++ch) s += part[(size_t)ch*NATTNR + e];
    int hc = e >> 12, ij = e & 4095, i = ij >> 6, j = ij & 63;
    attnR[e] = s * invqr[hc*64+i] * invkr[hc*64+j] * temp[3*NH + (hc>>3)];
  } else {
    // ---- k_dw ----
    int bb = blk - 10368;
    int ch = bb / 48; int y0 = (bb % 48) * 4;
    float (*rows)[192] = (float(*)[192])smem;
    for (int idx = t; idx < 6*48; idx += 256){
      int r = idx / 48, px4 = (idx % 48)*4;
      int yy = y0 - 1 + r;
      float4 v = {0.f,0.f,0.f,0.f};
      if (yy >= 0 && yy < IMG) v = *(const float4*)&u[(size_t)ch*HWP + (size_t)yy*IMG + px4];
      rows[r][px4] = v.x; rows[r][px4+1] = v.y; rows[r][px4+2] = v.z; rows[r][px4+3] = v.w;
    }
    float kw9[9];
    #pragma unroll
    for (int q = 0; q < 9; ++q) kw9[q] = dww[ch*9 + q];
    __syncthreads();
    int r = t >> 6, lane = t & 63;
    for (int kx = 0; kx < 3; ++kx){
      int px = lane + kx*64;
      float s = 0.f;
      #pragma unroll
      for (int dy = 0; dy < 3; ++dy){
        #pragma unroll
        for (int dx = -1; dx <= 1; ++dx){
          int xx = px + dx;
          if (xx >= 0 && xx < IMG) s += kw9[dy*3 + dx + 1] * rows[r+dy][xx];
        }
      }
      dwu[(size_t)ch*HWP + (size_t)(y0+r)*IMG + px] = s;
    }
  }
}

// ---------------- kC umbrella: k6c | k7b ----------------
__global__ __launch_bounds__(256) void kC(
    const float* __restrict__ attnGp, const float* __restrict__ vw,
    float* __restrict__ outa,
    const float* __restrict__ attnR, const float* __restrict__ rtalk,
    float* __restrict__ attnRp)
{
  __shared__ __align__(16) char smem[16512];
  int blk = blockIdx.x;
  int t = threadIdx.x;

  if (blk < 2304){
    float* P = (float*)smem;
    int n = blk % NWIN; int t2 = blk / NWIN;
    for (int l = t; l < KK*64; l += 256) P[l] = attnGp[(size_t)t2*KK*64 + l];
    __syncthreads();
    int i = t >> 2; int c0 = (t & 3)*2;
    size_t vbase = widx(t2, n, i, 16);
    float vg[8];
    #pragma unroll
    for (int d = 0; d < 8; ++d) vg[d] = vw[vbase + d];
    int hw = n/NWS, ww = n%NWS; int kh = i>>3, kwd = i&7;
    int Y = (hw*8+kh+SSH)%IMG, X = (ww*8+kwd+SSH)%IMG;
    for (int c = c0; c < c0+2; ++c){
      float o = 0.f;
      #pragma unroll
      for (int d = 0; d < 8; ++d) o += P[(i*8 + c)*8 + d]*vg[d];
      outa[((size_t)(64 + t2*CB + c)*IMG + Y)*IMG + X] = o;
    }
  } else {
    int bb = blk - 2304;
    int d = bb % CB; int t2 = bb / CB;
    float (*S)[64] = (float(*)[64])smem;
    float* wr2 = (float*)(smem + 16384);
    if (t < 32){ int h = t >> 3, c = t & 7; wr2[t] = rtalk[((size_t)(h*CB + c)*CB + d)*NH + t2]; }
    __syncthreads();
    int j = t & 63; int ig = t >> 6;
    float acc[16];
    #pragma unroll
    for (int p = 0; p < 16; ++p) acc[p] = 0.f;
    for (int hc = 0; hc < 32; ++hc){
      float w = wr2[hc];
      const float* Ar = attnR + (size_t)hc*KK*KK;
      #pragma unroll
      for (int p = 0; p < 16; ++p) acc[p] += w * Ar[(size_t)(ig*16+p)*KK + j];
    }
    #pragma unroll
    for (int p = 0; p < 16; ++p) S[ig*16+p][j] = acc[p];
    __syncthreads();
    for (int r = ig; r < 64; r += 4){
      float a = S[r][j];
      float m = wave_max(a);
      float e = __expf(a - m);
      attnRp[(((size_t)t2*CB + d)*KK + r)*KK + j] = e / wave_sum(e);
    }
  }
}

// ---------------- K7c: out_r PV ----------------
__global__ __launch_bounds__(256) void k7c(
    const float* __restrict__ attnRp, const float* __restrict__ vw, float* __restrict__ outa)
{
  int n = blockIdx.x % NWIN; int t2 = blockIdx.x / NWIN;
  __shared__ float vr[KK][CB];
  int t = threadIdx.x;
  for (int l = t; l < KK*CB; l += 256){
    int j = l >> 3, c = l & 7;
    vr[j][c] = vw[widx(t2, n, j, 24 + c)];
  }
  __syncthreads();
  int i = t & 63; int cg = t >> 6;
  int hw = n/NWS, ww = n%NWS; int kh = i>>3, kwd = i&7;
  int Y = (hw*8+kh+SSH)%IMG, X = (ww*8+kwd+SSH)%IMG;
  for (int c = cg*2; c < cg*2+2; ++c){
    const float* Pr = attnRp + (((size_t)t2*CB + c)*KK + i)*KK;
    float o = 0.f;
    for (int j = 0; j < KK; ++j) o += Pr[j]*vr[j][c];
    outa[((size_t)(96 + t2*CB + c)*IMG + Y)*IMG + X] = o;
  }
}

// ---------------- K8: channel means ----------------
__global__ __launch_bounds__(256) void k8_mean(const float* __restrict__ outa, float* __restrict__ meanb){
  int ch = blockIdx.x;
  const float4* p = (const float4*)(outa + (size_t)ch*HWP);
  float s = 0.f;
  for (int l = threadIdx.x; l < HWP/4; l += 256){
    float4 v = p[l]; s += v.x+v.y+v.z+v.w;
  }
  __shared__ float red[256];
  red[threadIdx.x] = s; __syncthreads();
  for (int k = 128; k > 0; k >>= 1){
    if (threadIdx.x < k) red[threadIdx.x] += red[threadIdx.x + k];
    __syncthreads();
  }
  if (threadIdx.x == 0) meanb[ch] = red[0] / (float)HWP;
}

// ---------------- K9a: out2z = (projw @ (outa*svec) + dwu) * zbuf ----------------
#define PADX 68
__global__ __launch_bounds__(256) void k9a(
    const float* __restrict__ outa, const float* __restrict__ meanb,
    const float* __restrict__ scaw, const float* __restrict__ scab,
    const float* __restrict__ projw, const float* __restrict__ dwu,
    const float* __restrict__ zbuf, float* __restrict__ out2z)
{
  __shared__ float WT[128][128];
  __shared__ float xsv[128][PADX];
  __shared__ float sv[128];
  int t = threadIdx.x;
  if (t < 128){
    float s = scab[t];
    const float* srow = scaw + (size_t)t*HD;
    for (int c = 0; c < HD; c += 4){
      float4 w = *(const float4*)&srow[c];
      float4 mm = *(const float4*)&meanb[c];
      s += w.x*mm.x + w.y*mm.y + w.z*mm.z + w.w*mm.w;
    }
    sv[t] = s;
  }
  for (int idx = t; idx < 4096; idx += 256){
    int o = idx & 127; int c4 = (idx >> 7) * 4;
    float4 w = *(const float4*)&projw[(size_t)o*HD + c4];
    WT[c4][o] = w.x; WT[c4+1][o] = w.y; WT[c4+2][o] = w.z; WT[c4+3][o] = w.w;
  }
  int px4 = (t & 15) * 4; int og8 = (t >> 4) * 8;
  for (int tile = 0; tile < 2; ++tile){
    int tid = blockIdx.x * 2 + tile;
    int y = tid / 3, x0 = (tid % 3) * 64;
    size_t sb = (size_t)y*IMG + x0;
    __syncthreads();
    for (int idx = t; idx < 2048; idx += 256){
      int c = idx >> 4; int p4 = (idx & 15) * 4;
      float4 v = *(const float4*)&outa[(size_t)c*HWP + sb + p4];
      float s = sv[c];
      xsv[c][p4] = v.x*s; xsv[c][p4+1] = v.y*s; xsv[c][p4+2] = v.z*s; xsv[c][p4+3] = v.w*s;
    }
    __syncthreads();
    float acc[8][4];
    #pragma unroll
    for (int a = 0; a < 8; ++a){ acc[a][0]=0.f; acc[a][1]=0.f; acc[a][2]=0.f; acc[a][3]=0.f; }
    for (int c = 0; c < 128; ++c){
      float4 xv = *(const float4*)&xsv[c][px4];
      float4 wA = *(const float4*)&WT[c][og8];
      float4 wB = *(const float4*)&WT[c][og8+4];
      float w8[8] = {wA.x,wA.y,wA.z,wA.w,wB.x,wB.y,wB.z,wB.w};
      #pragma unroll
      for (int a = 0; a < 8; ++a){
        acc[a][0] += w8[a]*xv.x; acc[a][1] += w8[a]*xv.y;
        acc[a][2] += w8[a]*xv.z; acc[a][3] += w8[a]*xv.w;
      }
    }
    #pragma unroll
    for (int oo = 0; oo < 8; ++oo){
      int o = og8 + oo;
      size_t off = (size_t)o*HWP + sb + px4;
      float4 d = *(const float4*)&dwu[off];
      float4 z = *(const float4*)&zbuf[off];
      float4 r;
      r.x = (acc[oo][0]+d.x)*z.x; r.y = (acc[oo][1]+d.y)*z.y;
      r.z = (acc[oo][2]+d.z)*z.z; r.w = (acc[oo][3]+d.w)*z.w;
      *(float4*)&out2z[off] = r;
    }
  }
}

// ---------------- K9b: dout = projow @ out2z ----------------
__global__ __launch_bounds__(256) void k9b(
    const float* __restrict__ out2z, const float* __restrict__ projow,
    float* __restrict__ dout, int bsel)
{
  __shared__ float WT2[128][64];
  __shared__ float xsv[128][PADX];
  int t = threadIdx.x;
  for (int idx = t; idx < 2048; idx += 256){
    int o = idx & 63; int c4 = (idx >> 6) * 4;
    float4 w = *(const float4*)&projow[(size_t)o*HD + c4];
    WT2[c4][o] = w.x; WT2[c4+1][o] = w.y; WT2[c4+2][o] = w.z; WT2[c4+3][o] = w.w;
  }
  int px4 = (t & 15) * 4; int og4 = (t >> 4) * 4;
  for (int tile = 0; tile < 2; ++tile){
    int tid = blockIdx.x * 2 + tile;
    int y = tid / 3, x0 = (tid % 3) * 64;
    size_t sb = (size_t)y*IMG + x0;
    __syncthreads();
    for (int idx = t; idx < 2048; idx += 256){
      int c = idx >> 4; int p4 = (idx & 15) * 4;
      float4 v = *(const float4*)&out2z[(size_t)c*HWP + sb + p4];
      xsv[c][p4] = v.x; xsv[c][p4+1] = v.y; xsv[c][p4+2] = v.z; xsv[c][p4+3] = v.w;
    }
    __syncthreads();
    float acc[4][4];
    #pragma unroll
    for (int a = 0; a < 4; ++a){ acc[a][0]=0.f; acc[a][1]=0.f; acc[a][2]=0.f; acc[a][3]=0.f; }
    for (int c = 0; c < 128; ++c){
      float4 xv = *(const float4*)&xsv[c][px4];
      float4 w4 = *(const float4*)&WT2[c][og4];
      float w4a[4] = {w4.x,w4.y,w4.z,w4.w};
      #pragma unroll
      for (int a = 0; a < 4; ++a){
        acc[a][0] += w4a[a]*xv.x; acc[a][1] += w4a[a]*xv.y;
        acc[a][2] += w4a[a]*xv.z; acc[a][3] += w4a[a]*xv.w;
      }
    }
    #pragma unroll
    for (int oo = 0; oo < 4; ++oo){
      int o = og4 + oo;
      float4 r; r.x = acc[oo][0]; r.y = acc[oo][1]; r.z = acc[oo][2]; r.w = acc[oo][3];
      *(float4*)&dout[(size_t)(bsel*CIN + o)*HWP + sb + px4] = r;
    }
  }
}

// ---------------- launch ----------------
extern "C" void kernel_launch(void* const* d_in, const int* in_sizes, int n_in,
                              void* d_out, int out_size, void* d_ws, size_t ws_size,
                              hipStream_t stream)
{
  const float* x     = (const float*)d_in[0];
  const float* wquz  = (const float*)d_in[1];
  const float* wkv   = (const float*)d_in[2];
  const float* temp  = (const float*)d_in[3];
  const float* rtalk = (const float*)d_in[4];
  const float* gtalk = (const float*)d_in[5];
  const float* btw   = (const float*)d_in[6];
  const float* ltw   = (const float*)d_in[7];
  const float* dww   = (const float*)d_in[8];
  const float* projw = (const float*)d_in[9];
  const float* projow= (const float*)d_in[10];
  const float* scaw  = (const float*)d_in[11];
  const float* scab  = (const float*)d_in[12];
  float* dout = (float*)d_out;

  float* ws = (float*)d_ws;
  float* qw    = ws;                  // NQK16
  float* kw    = qw + NQK16;          // NQK16
  float* vw    = kw + NQK16;          // NV32
  float* qg    = vw + NV32;           // NGR
  float* kg    = qg + NGR;            // NGR
  float* qr    = kg + NGR;            // NGR
  float* kr    = qr + NGR;            // NGR
  float* u     = kr + NGR;            // NSP
  float* zbuf  = u + NSP;             // NSP
  float* outa  = zbuf + NSP;          // NSP
  float* attnB = outa + NSP;          // NATTNB
  float* attnL = attnB + NATTNB;      // NATTNL
  float* attnG = attnL + NATTNL;      // NATTNG
  float* attnGp= attnG + NATTNG;      // NATTNG
  float* part  = attnGp + NATTNG;     // NPART
  float* attnR = part + NPART;        // NATTNR
  float* attnRp= attnR + NATTNR;      // NATTNR
  float* invqr = attnRp + NATTNR;     // 2048
  float* invkr = invqr + 2048;        // 2048
  float* meanb = invkr + 2048;        // 128
  // Aliases (lifetime-disjoint):
  float* dwu   = qw;                  // qw/kw dead after kA; 2*NQK16 == NSP
  float* out2z = attnB;               // attnB dead after kB

  for (int b = 0; b < BB; ++b){
    k1_proj<<<IMG*12, 256, 0, stream>>>(x, wquz, wkv, qw, kw, vw, qg, kg, qr, kr, u, zbuf, b);

    kA<<<1696, 256, 0, stream>>>(qw, kw, qg, kg, qr, kr, temp,
                                 attnB, attnL, attnG, part, invqr, invkr);

    kB<<<16512, 256, 0, stream>>>(attnB, btw, vw, outa, attnL, ltw,
                                  attnG, gtalk, attnGp, part, invqr, invkr, temp, attnR,
                                  u, dww, dwu);

    kC<<<2336, 256, 0, stream>>>(attnGp, vw, outa, attnR, rtalk, attnRp);

    k7c<<<NH*NWIN, 256, 0, stream>>>(attnRp, vw, outa);

    k8_mean<<<HD, 256, 0, stream>>>(outa, meanb);

    k9a<<<288, 256, 0, stream>>>(outa, meanb, scaw, scab, projw, dwu, zbuf, out2z);
    k9b<<<288, 256, 0, stream>>>(out2z, projow, dout, b);
  }
}

// Round 13
// 1194.364 us; speedup vs baseline: 1.0671x; 1.0671x over previous
//
#include <hip/hip_runtime.h>
#include <hip/hip_fp16.h>
#include <cstdint>
#include <cstddef>

// ---------------- problem constants ----------------
#define BB   4      // batch
#define CIN  64     // input channels
#define HD   128    // h_dim
#define NH   4      // heads
#define CHW  32     // channels per head
#define CB   8      // channels per branch
#define IMG  192    // H = W
#define SSH  4      // shift
#define NWS  24     // windows per side
#define NWIN 576    // windows total
#define KK   64     // window elements (8x8)
#define HWP  (IMG*IMG)

// per-batch buffer sizes (floats)
static const size_t NQK16  = (size_t)NH*NWIN*KK*16;   // 2,359,296
static const size_t NV32   = (size_t)NH*NWIN*KK*CHW;  // 4,718,592
static const size_t NGR    = (size_t)NH*KK*NWIN*CB;   // 1,179,648
static const size_t NSP    = (size_t)HD*HWP;          // 4,718,592
static const size_t NATTNB = (size_t)NH*NWIN*KK*KK;   // 9,437,184 (fp16 elems = NSP floats)
static const size_t NATTNL = (size_t)NH*NWIN*64;      // 147,456
static const size_t NATTNG = (size_t)NH*KK*64;        // 16,384
static const size_t NATTNR = (size_t)NH*CB*KK*KK;     // 131,072
static const size_t NPART  = (size_t)8*NATTNR;        // 1,048,576

// ---------------- helpers ----------------
__device__ inline float wave_max(float v){
  #pragma unroll
  for (int s=1;s<64;s<<=1) v = fmaxf(v, __shfl_xor(v, s));
  return v;
}
__device__ inline float wave_sum(float v){
  #pragma unroll
  for (int s=1;s<64;s<<=1) v += __shfl_xor(v, s);
  return v;
}
__device__ inline float g8_max(float v){
  v = fmaxf(v, __shfl_xor(v,1)); v = fmaxf(v, __shfl_xor(v,2)); v = fmaxf(v, __shfl_xor(v,4));
  return v;
}
__device__ inline float g8_sum(float v){
  v += __shfl_xor(v,1); v += __shfl_xor(v,2); v += __shfl_xor(v,4);
  return v;
}
__device__ inline int regionc(int y){ return (y < IMG-8) ? 0 : ((y < IMG-4) ? 1 : 2); }

__device__ inline size_t widx(int h,int n,int i,int c){
  return (((size_t)h*NWIN + n)*KK + i)*CHW + c;
}
__device__ inline size_t widx16(int h,int n,int i,int c){
  return (((size_t)h*NWIN + n)*KK + i)*16 + c;
}
__device__ inline size_t gidx(int h,int i,int n,int c){
  return (((size_t)(h*KK + i))*NWIN + n)*CB + c;
}
__device__ inline size_t ridx(int h,int c,int n,int i){
  return (((size_t)(h*CB + c))*NWIN + n)*KK + i;
}

// ---------------- K1: projections (wave-coherent stores + LDS-transposed u/z) ----------------
__global__ __launch_bounds__(256) void k1_proj(
    const float* __restrict__ x, const float* __restrict__ wquz, const float* __restrict__ wkv,
    float* __restrict__ qw, float* __restrict__ kw, float* __restrict__ vw,
    float* __restrict__ qg, float* __restrict__ kg,
    float* __restrict__ qr, float* __restrict__ kr,
    float* __restrict__ u, float* __restrict__ zbuf, int bsel)
{
  __shared__ float xs[64][20];
  __shared__ float tb[128][17];   // transpose buffer for u / z spatial stores
  int blk = blockIdx.x;
  int xc = blk % 12, y = blk / 12;
  int x0 = xc*16;
  int t = threadIdx.x;
  {
    int c = t >> 2, p4 = (t & 3)*4;
    float4 v = *(const float4*)&x[((size_t)(bsel*CIN+c)*IMG + y)*IMG + x0 + p4];
    *(float4*)&xs[c][p4] = v;
  }
  int py  = (y + IMG - SSH) % IMG;
  int kh  = py & 7, hwq = py >> 3;
  int wwA = ((x0 - SSH + IMG) % IMG) >> 3;
  int wwB = x0 >> 3;
  int wwC = (x0 + 8) >> 3;
  int pnA = hwq*NWS + wwA, pnB = hwq*NWS + wwB, pnC = hwq*NWS + wwC;
  int piA = kh*8 + 4, piB = kh*8, piC = kh*8;
  #define PN_(p) ((p)<4 ? pnA : ((p)<12 ? pnB : pnC))
  #define PI_(p) ((p)<4 ? (piA+(p)) : ((p)<12 ? (piB+(p)-4) : (piC+(p)-12)))
  __syncthreads();

  int o;
  if (t < 64)       o = (t>>4)*32 + (t&15);
  else if (t < 96)  o = ((t-64)>>3)*32 + 16 + (t&7);
  else if (t < 128) o = ((t-96)>>3)*32 + 24 + (t&7);
  else              o = t;

  // ---- pass 0: q (waves 0-1) / u -> LDS (waves 2-3) ----
  {
    const float* wr = wquz + (size_t)o*CIN;
    float acc[16];
    #pragma unroll
    for (int p = 0; p < 16; ++p) acc[p] = 0.f;
    for (int cc = 0; cc < 64; cc += 4){
      float4 w4 = *(const float4*)(wr + cc);
      #pragma unroll
      for (int p = 0; p < 16; ++p){
        acc[p] += w4.x * xs[cc  ][p];
        acc[p] += w4.y * xs[cc+1][p];
        acc[p] += w4.z * xs[cc+2][p];
        acc[p] += w4.w * xs[cc+3][p];
      }
    }
    if (t < 64){
      int h = t >> 4, c = t & 15;
      #pragma unroll
      for (int p = 0; p < 16; ++p) qw[widx16(h,PN_(p),PI_(p),c)] = acc[p];
    } else if (t < 96){
      int h = (t-64) >> 3, cg = t & 7;
      #pragma unroll
      for (int p = 0; p < 16; ++p) qg[gidx(h,PI_(p),PN_(p),cg)] = acc[p];
    } else if (t < 128){
      int h = (t-96) >> 3, cr = t & 7;
      *(float4*)&qr[ridx(h,cr,pnA,piA)]   = make_float4(acc[0],acc[1],acc[2],acc[3]);
      *(float4*)&qr[ridx(h,cr,pnB,piB)]   = make_float4(acc[4],acc[5],acc[6],acc[7]);
      *(float4*)&qr[ridx(h,cr,pnB,piB+4)] = make_float4(acc[8],acc[9],acc[10],acc[11]);
      *(float4*)&qr[ridx(h,cr,pnC,piC)]   = make_float4(acc[12],acc[13],acc[14],acc[15]);
    } else {
      int ch = o - 128;
      #pragma unroll
      for (int p = 0; p < 16; ++p) tb[ch][p] = acc[p];
    }
  }
  __syncthreads();
  // transposed u store: lane = pixel
  {
    int px = t & 15, chg = t >> 4;
    size_t ub = (size_t)y*IMG + x0 + px;
    #pragma unroll
    for (int cc = 0; cc < 8; ++cc){
      int ch = chg*8 + cc;
      u[(size_t)ch*HWP + ub] = tb[ch][px];
    }
  }

  // ---- pass 1: k (waves 0-1) / v (waves 2-3) ----
  {
    const float* wr = wkv + (size_t)o*CIN;
    float acc[16];
    #pragma unroll
    for (int p = 0; p < 16; ++p) acc[p] = 0.f;
    for (int cc = 0; cc < 64; cc += 4){
      float4 w4 = *(const float4*)(wr + cc);
      #pragma unroll
      for (int p = 0; p < 16; ++p){
        acc[p] += w4.x * xs[cc  ][p];
        acc[p] += w4.y * xs[cc+1][p];
        acc[p] += w4.z * xs[cc+2][p];
        acc[p] += w4.w * xs[cc+3][p];
      }
    }
    if (t < 64){
      int h = t >> 4, c = t & 15;
      #pragma unroll
      for (int p = 0; p < 16; ++p) kw[widx16(h,PN_(p),PI_(p),c)] = acc[p];
    } else if (t < 96){
      int h = (t-64) >> 3, cg = t & 7;
      #pragma unroll
      for (int p = 0; p < 16; ++p) kg[gidx(h,PI_(p),PN_(p),cg)] = acc[p];
    } else if (t < 128){
      int h = (t-96) >> 3, cr = t & 7;
      *(float4*)&kr[ridx(h,cr,pnA,piA)]   = make_float4(acc[0],acc[1],acc[2],acc[3]);
      *(float4*)&kr[ridx(h,cr,pnB,piB)]   = make_float4(acc[4],acc[5],acc[6],acc[7]);
      *(float4*)&kr[ridx(h,cr,pnB,piB+4)] = make_float4(acc[8],acc[9],acc[10],acc[11]);
      *(float4*)&kr[ridx(h,cr,pnC,piC)]   = make_float4(acc[12],acc[13],acc[14],acc[15]);
    } else {
      int oc = o - 128; int h = oc >> 5, c = oc & 31;
      #pragma unroll
      for (int p = 0; p < 16; ++p) vw[widx(h,PN_(p),PI_(p),c)] = acc[p];
    }
  }

  // ---- pass 2: z -> LDS -> transposed store ----
  __syncthreads();
  {
    int zr = t >> 1, ph = t & 1;
    const float* wr = wquz + (size_t)(256 + zr)*CIN;
    int pb = ph*8;
    float acc[8];
    #pragma unroll
    for (int p = 0; p < 8; ++p) acc[p] = 0.f;
    for (int cc = 0; cc < 64; cc += 4){
      float4 w4 = *(const float4*)(wr + cc);
      #pragma unroll
      for (int p = 0; p < 8; ++p){
        acc[p] += w4.x * xs[cc  ][pb+p];
        acc[p] += w4.y * xs[cc+1][pb+p];
        acc[p] += w4.z * xs[cc+2][pb+p];
        acc[p] += w4.w * xs[cc+3][pb+p];
      }
    }
    #pragma unroll
    for (int p = 0; p < 8; ++p) tb[zr][pb+p] = acc[p];
  }
  __syncthreads();
  {
    int px = t & 15, chg = t >> 4;
    size_t zb = (size_t)y*IMG + x0 + px;
    #pragma unroll
    for (int cc = 0; cc < 8; ++cc){
      int ch = chg*8 + cc;
      zbuf[(size_t)ch*HWP + zb] = tb[ch][px];
    }
  }
  #undef PN_
  #undef PI_
}

// ---------------- kA umbrella: k3(fp16 out) | k5a | k6a(+g-norm) | k7a | kNr ----------------
__global__ __launch_bounds__(256) void kA(
    const float* __restrict__ qw, const float* __restrict__ kw,
    const float* __restrict__ qg, const float* __restrict__ kg,
    const float* __restrict__ qr, const float* __restrict__ kr,
    const float* __restrict__ temp,
    __half* __restrict__ attnB, float* __restrict__ attnL,
    float* __restrict__ attnG, float* __restrict__ part,
    float* __restrict__ invqr, float* __restrict__ invkr)
{
  __shared__ __align__(16) char smem[36864];
  int blk = blockIdx.x;
  int t = threadIdx.x;

  if (blk < 576){
    float (*qs)[64][8] = (float(*)[64][8])smem;
    int wv = t >> 6, j = t & 63;
    int gid = blk*4 + wv;
    int n = gid % NWIN, h = gid / NWIN;
    size_t base = widx16(h,n,j,0);
    float q8[CB], k8[CB];
    float sq = 0.f, sk2 = 0.f;
    #pragma unroll
    for (int c = 0; c < CB; ++c){
      q8[c] = qw[base+c]; sq += q8[c]*q8[c];
      k8[c] = kw[base+c]; sk2 += k8[c]*k8[c];
    }
    float invq = 1.f/fmaxf(sqrtf(sq),1e-12f), invk = 1.f/fmaxf(sqrtf(sk2),1e-12f);
    #pragma unroll
    for (int c = 0; c < CB; ++c){ qs[wv][j][c] = q8[c]*invq; k8[c] *= invk; }
    __syncthreads();
    float tmp = temp[h];
    __half* orow = attnB + (size_t)gid*KK*KK;
    for (int i = 0; i < KK; ++i){
      float a = 0.f;
      #pragma unroll
      for (int c = 0; c < CB; ++c) a += qs[wv][i][c]*k8[c];
      orow[(size_t)i*KK + j] = __float2half(a * tmp);
    }
  } else if (blk < 1152){
    int b2 = blk - 576;
    float (*qs)[64][8] = (float(*)[64][8])smem;
    float (*ks)[64][8] = (float(*)[64][8])(smem + 8192);
    float (*invqA)[8] = (float(*)[8])(smem + 16384);
    float (*invkA)[8] = (float(*)[8])(smem + 16384 + 128);
    int wv = t >> 6, tl = t & 63;
    int gid = b2*4 + wv;
    int n = gid % NWIN, h = gid / NWIN;
    size_t base = widx16(h,n,tl,8);
    #pragma unroll
    for (int c = 0; c < CB; ++c){ qs[wv][tl][c] = qw[base+c]; ks[wv][tl][c] = kw[base+c]; }
    __syncthreads();
    int c8 = tl & 7, ig = tl >> 3;
    float sq = 0.f, sk2 = 0.f;
    for (int i = ig; i < KK; i += 8){
      float a = qs[wv][i][c8]; sq += a*a;
      float b = ks[wv][i][c8]; sk2 += b*b;
    }
    #pragma unroll
    for (int m = 8; m < 64; m <<= 1){ sq += __shfl_xor(sq,m); sk2 += __shfl_xor(sk2,m); }
    if (tl < 8){ invqA[wv][tl] = 1.f/fmaxf(sqrtf(sq),1e-12f); invkA[wv][tl] = 1.f/fmaxf(sqrtf(sk2),1e-12f); }
    __syncthreads();
    int c = tl >> 3, d = tl & 7;
    float a = 0.f;
    for (int i = 0; i < KK; ++i) a += qs[wv][i][c]*ks[wv][i][d];
    attnL[(size_t)gid*64 + tl] = a * invqA[wv][c] * invkA[wv][d] * temp[NH + h];
  } else if (blk < 1408){
    int b2 = blk - 1152;
    int i = b2 & 63, h = b2 >> 6;
    float* sq = (float*)smem;
    float* sk = sq + 512;
    float (*redA)[64] = (float(*)[64])(smem + 4096);
    float (*redQ)[64] = (float(*)[64])(smem + 4096 + 1024);
    float (*redK)[64] = (float(*)[64])(smem + 4096 + 2048);
    size_t base = ((size_t)(h*KK+i))*NWIN*CB;
    int np = t >> 6, cd = t & 63, c = cd >> 3, d = cd & 7;
    float a = 0.f, qs2 = 0.f, ks2 = 0.f;
    for (int n0 = 0; n0 < NWIN; n0 += 64){
      __syncthreads();
      for (int idx = t; idx < 512; idx += 256){
        sq[idx] = qg[base + (size_t)n0*CB + idx];
        sk[idx] = kg[base + (size_t)n0*CB + idx];
      }
      __syncthreads();
      for (int nn = np; nn < 64; nn += 4){
        float qv = sq[nn*8+c], kv = sk[nn*8+d];
        a += qv*kv; qs2 += qv*qv; ks2 += kv*kv;
      }
    }
    __syncthreads();
    redA[np][cd] = a; redQ[np][cd] = qs2; redK[np][cd] = ks2;
    __syncthreads();
    if (t < 64){
      float at = redA[0][t]+redA[1][t]+redA[2][t]+redA[3][t];
      float qt = redQ[0][t]+redQ[1][t]+redQ[2][t]+redQ[3][t];
      float kt = redK[0][t]+redK[1][t]+redK[2][t]+redK[3][t];
      at *= (1.f/fmaxf(sqrtf(qt),1e-12f)) * (1.f/fmaxf(sqrtf(kt),1e-12f)) * temp[2*NH + h];
      attnG[(size_t)(h*KK+i)*64 + t] = at;
    }
  } else if (blk < 1664){
    int b2 = blk - 1408;
    int chunk = b2 >> 5, hc = b2 & 31;
    int n0 = chunk*72;
    float* sq = (float*)smem;
    float* sk = sq + 72*64;
    size_t base = (size_t)hc*NWIN*KK + (size_t)n0*KK;
    for (int idx = t; idx < 72*64/4; idx += 256){
      *(float4*)&sq[idx*4] = *(const float4*)&qr[base + (size_t)idx*4];
      *(float4*)&sk[idx*4] = *(const float4*)&kr[base + (size_t)idx*4];
    }
    __syncthreads();
    int j = t & 63, ig = t >> 6;
    float acc[16];
    #pragma unroll
    for (int p = 0; p < 16; ++p) acc[p] = 0.f;
    for (int nn = 0; nn < 72; ++nn){
      float kv = sk[nn*64+j];
      #pragma unroll
      for (int p = 0; p < 16; ++p) acc[p] += sq[nn*64 + ig*16 + p]*kv;
    }
    float* ob = part + (size_t)b2*4096;
    #pragma unroll
    for (int p = 0; p < 16; ++p) ob[(size_t)(ig*16+p)*64 + j] = acc[p];
  } else {
    int hc = blk - 1664;
    float (*rq)[64] = (float(*)[64])smem;
    float (*rk)[64] = (float(*)[64])(smem + 1024);
    size_t base = (size_t)hc*NWIN*KK;
    int i = t & 63, ng = t >> 6;
    float sq = 0.f, sk2 = 0.f;
    for (int n = ng; n < NWIN; n += 4){
      float a = qr[base + (size_t)n*KK + i]; sq  += a*a;
      float b = kr[base + (size_t)n*KK + i]; sk2 += b*b;
    }
    rq[ng][i] = sq; rk[ng][i] = sk2;
    __syncthreads();
    if (t < 64){
      float s = rq[0][t]+rq[1][t]+rq[2][t]+rq[3][t];
      invqr[hc*KK + t] = 1.f/fmaxf(sqrtf(s),1e-12f);
    } else if (t < 128){
      int i2 = t - 64;
      float s = rk[0][i2]+rk[1][i2]+rk[2][i2]+rk[3][i2];
      invkr[hc*KK + i2] = 1.f/fmaxf(sqrtf(s),1e-12f);
    }
  }
}

// ---------------- kB umbrella: k4(fp16 in, linear order) | k5b | k6b | kRed | k_dw ----------------
__global__ __launch_bounds__(256) void kB(
    const __half* __restrict__ attnB, const float* __restrict__ btw,
    const float* __restrict__ vw, float* __restrict__ outa,
    const float* __restrict__ attnL, const float* __restrict__ ltw,
    const float* __restrict__ attnG, const float* __restrict__ gtalk,
    float* __restrict__ attnGp,
    const float* __restrict__ part, const float* __restrict__ invqr,
    const float* __restrict__ invkr, const float* __restrict__ temp,
    float* __restrict__ attnR,
    const float* __restrict__ u, const float* __restrict__ dww,
    float* __restrict__ dwu)
{
  __shared__ __align__(16) char smem[12800];
  int blk = blockIdx.x;
  int t = threadIdx.x;

  if (blk < 9216){
    // ---- k4: talk-conv direct from fp16 attnB + mask + softmax + PV ----
    float (*pbuf)[4][66] = (float(*)[4][66])smem;
    float (*vv)[8][66]   = (float(*)[8][66])(smem + 4224);
    int ig = blk / NWIN, n = blk % NWIN;
    int i0 = ig*4;
    int hw = n / NWS, ww = n % NWS;
    int w = t >> 6, l = t & 63;
    {
      size_t vb = widx(w, n, l, 0);
      float4 va = *(const float4*)&vw[vb];
      float4 vb4 = *(const float4*)&vw[vb + 4];
      vv[w][0][l] = va.x;  vv[w][1][l] = va.y;  vv[w][2][l] = va.z;  vv[w][3][l] = va.w;
      vv[w][4][l] = vb4.x; vv[w][5][l] = vb4.y; vv[w][6][l] = vb4.z; vv[w][7][l] = vb4.w;
    }
    int i = i0 + w;
    float a0 = 0.f, a1 = 0.f, a2 = 0.f, a3 = 0.f;
    #pragma unroll
    for (int nb = 0; nb < 9; ++nb){
      const int dy = nb/3 - 1, dx = nb%3 - 1;
      int hw2 = hw + dy, ww2 = ww + dx;
      if (hw2 >= 0 && hw2 < NWS && ww2 >= 0 && ww2 < NWS){
        int n2 = hw2*NWS + ww2;
        #pragma unroll
        for (int h = 0; h < 4; ++h){
          float r = __half2float(attnB[((size_t)(h*NWIN + n2)*KK + i)*KK + l]);
          a0 += btw[(0*4 + h)*9 + nb] * r;
          a1 += btw[(1*4 + h)*9 + nb] * r;
          a2 += btw[(2*4 + h)*9 + nb] * r;
          a3 += btw[(3*4 + h)*9 + nb] * r;
        }
      }
    }
    int kh = i >> 3, kwd = i & 7;
    int cntI = regionc(hw*8 + kh)*3 + regionc(ww*8 + kwd);
    int cntJ = regionc(hw*8 + (l>>3))*3 + regionc(ww*8 + (l&7));
    float mval = (cntI != cntJ) ? -100.f : 0.f;
    a0 += mval; a1 += mval; a2 += mval; a3 += mval;
    {
      float m0 = wave_max(a0); float e0 = __expf(a0 - m0); pbuf[0][w][l] = e0 / wave_sum(e0);
      float m1 = wave_max(a1); float e1 = __expf(a1 - m1); pbuf[1][w][l] = e1 / wave_sum(e1);
      float m2 = wave_max(a2); float e2 = __expf(a2 - m2); pbuf[2][w][l] = e2 / wave_sum(e2);
      float m3 = wave_max(a3); float e3 = __expf(a3 - m3); pbuf[3][w][l] = e3 / wave_sum(e3);
    }
    __syncthreads();
    {
      int i2 = l >> 4, c = (l >> 1) & 7, jq = l & 1;
      const float* pr = &pbuf[w][i2][jq*32];
      const float* vr = &vv[w][c][jq*32];
      float s = 0.f;
      #pragma unroll
      for (int q = 0; q < 32; ++q) s += pr[q] * vr[q];
      s += __shfl_xor(s, 1);
      if (jq == 0){
        int ii = i0 + i2;
        int khh = ii >> 3, kww = ii & 7;
        int Y = (hw*8 + khh + SSH) % IMG;
        int X = (ww*8 + kww + SSH) % IMG;
        outa[((size_t)(w*CB + c)*HWP) + (size_t)Y*IMG + X] = s;
      }
    }
  } else if (blk < 9792){
    // ---- k5b ----
    int n = blk - 9216;
    int hw = n/NWS, ww = n%NWS;
    float (*rows)[9][64] = (float(*)[9][64])smem;
    float* wt = (float*)(smem + 9216);
    float (*P)[8][8] = (float(*)[8][8])(smem + 9792);
    if (t < NH*NH*9) wt[t] = ltw[t];
    for (int l = t; l < NH*9*64; l += 256){
      int h = l/(9*64); int nb = (l/64)%9; int cd = l & 63;
      int dy = nb/3-1, dx = nb%3-1; int hw2 = hw+dy, ww2 = ww+dx;
      float v = 0.f;
      if (hw2>=0 && hw2<NWS && ww2>=0 && ww2<NWS)
        v = attnL[((size_t)h*NWIN + hw2*NWS + ww2)*64 + cd];
      rows[h][nb][cd] = v;
    }
    __syncthreads();
    int tt = t >> 6; int cd = t & 63; int c = cd >> 3, d = cd & 7;
    float a = 0.f;
    #pragma unroll
    for (int h = 0; h < NH; ++h)
      #pragma unroll
      for (int nb = 0; nb < 9; ++nb)
        a += wt[(tt*NH + h)*9 + nb] * rows[h][nb][cd];
    float m = g8_max(a);
    float e = __expf(a - m);
    P[tt][c][d] = e / g8_sum(e);
    __syncthreads();
    int i = t & 63;
    size_t vbase = widx(tt, n, i, 8);
    float vl[CB];
    #pragma unroll
    for (int d2 = 0; d2 < CB; ++d2) vl[d2] = vw[vbase + d2];
    int kh = i>>3, kwd = i&7;
    int Y = (hw*8+kh+SSH)%IMG, X = (ww*8+kwd+SSH)%IMG;
    #pragma unroll
    for (int c2 = 0; c2 < CB; ++c2){
      float o = 0.f;
      #pragma unroll
      for (int d2 = 0; d2 < CB; ++d2) o += P[tt][c2][d2]*vl[d2];
      outa[((size_t)(32 + tt*CB + c2)*IMG + Y)*IMG + X] = o;
    }
  } else if (blk < 9856){
    // ---- k6b ----
    int bb = blk - 9792;
    int w = t >> 6, cd = t & 63;
    int idx = bb*4 + w;
    int l = idx & 63, t2 = idx >> 6;
    float a = 0.f;
    for (int h = 0; h < NH; ++h)
      for (int k = 0; k < KK; ++k)
        a += gtalk[((size_t)(h*KK + k)*KK + l)*NH + t2] * attnG[((size_t)h*KK + k)*64 + cd];
    float m = g8_max(a);
    float e = __expf(a - m);
    attnGp[((size_t)t2*KK + l)*64 + cd] = e / g8_sum(e);
  } else if (blk < 10368){
    // ---- kRed ----
    int e = (blk - 9856)*256 + t;
    float s = 0.f;
    #pragma unroll
    for (int ch = 0; ch < 8; ++ch) s += part[(size_t)ch*NATTNR + e];
    int hc = e >> 12, ij = e & 4095, i = ij >> 6, j = ij & 63;
    attnR[e] = s * invqr[hc*64+i] * invkr[hc*64+j] * temp[3*NH + (hc>>3)];
  } else {
    // ---- k_dw ----
    int bb = blk - 10368;
    int ch = bb / 48; int y0 = (bb % 48) * 4;
    float (*rows)[192] = (float(*)[192])smem;
    for (int idx = t; idx < 6*48; idx += 256){
      int r = idx / 48, px4 = (idx % 48)*4;
      int yy = y0 - 1 + r;
      float4 v = {0.f,0.f,0.f,0.f};
      if (yy >= 0 && yy < IMG) v = *(const float4*)&u[(size_t)ch*HWP + (size_t)yy*IMG + px4];
      rows[r][px4] = v.x; rows[r][px4+1] = v.y; rows[r][px4+2] = v.z; rows[r][px4+3] = v.w;
    }
    float kw9[9];
    #pragma unroll
    for (int q = 0; q < 9; ++q) kw9[q] = dww[ch*9 + q];
    __syncthreads();
    int r = t >> 6, lane = t & 63;
    for (int kx = 0; kx < 3; ++kx){
      int px = lane + kx*64;
      float s = 0.f;
      #pragma unroll
      for (int dy = 0; dy < 3; ++dy){
        #pragma unroll
        for (int dx = -1; dx <= 1; ++dx){
          int xx = px + dx;
          if (xx >= 0 && xx < IMG) s += kw9[dy*3 + dx + 1] * rows[r+dy][xx];
        }
      }
      dwu[(size_t)ch*HWP + (size_t)(y0+r)*IMG + px] = s;
    }
  }
}

// ---------------- kC umbrella: k6c | k7b ----------------
__global__ __launch_bounds__(256) void kC(
    const float* __restrict__ attnGp, const float* __restrict__ vw,
    float* __restrict__ outa,
    const float* __restrict__ attnR, const float* __restrict__ rtalk,
    float* __restrict__ attnRp)
{
  __shared__ __align__(16) char smem[16512];
  int blk = blockIdx.x;
  int t = threadIdx.x;

  if (blk < 2304){
    float* P = (float*)smem;
    int n = blk % NWIN; int t2 = blk / NWIN;
    for (int l = t; l < KK*64; l += 256) P[l] = attnGp[(size_t)t2*KK*64 + l];
    __syncthreads();
    int i = t >> 2; int c0 = (t & 3)*2;
    size_t vbase = widx(t2, n, i, 16);
    float vg[8];
    #pragma unroll
    for (int d = 0; d < 8; ++d) vg[d] = vw[vbase + d];
    int hw = n/NWS, ww = n%NWS; int kh = i>>3, kwd = i&7;
    int Y = (hw*8+kh+SSH)%IMG, X = (ww*8+kwd+SSH)%IMG;
    for (int c = c0; c < c0+2; ++c){
      float o = 0.f;
      #pragma unroll
      for (int d = 0; d < 8; ++d) o += P[(i*8 + c)*8 + d]*vg[d];
      outa[((size_t)(64 + t2*CB + c)*IMG + Y)*IMG + X] = o;
    }
  } else {
    int bb = blk - 2304;
    int d = bb % CB; int t2 = bb / CB;
    float (*S)[64] = (float(*)[64])smem;
    float* wr2 = (float*)(smem + 16384);
    if (t < 32){ int h = t >> 3, c = t & 7; wr2[t] = rtalk[((size_t)(h*CB + c)*CB + d)*NH + t2]; }
    __syncthreads();
    int j = t & 63; int ig = t >> 6;
    float acc[16];
    #pragma unroll
    for (int p = 0; p < 16; ++p) acc[p] = 0.f;
    for (int hc = 0; hc < 32; ++hc){
      float w = wr2[hc];
      const float* Ar = attnR + (size_t)hc*KK*KK;
      #pragma unroll
      for (int p = 0; p < 16; ++p) acc[p] += w * Ar[(size_t)(ig*16+p)*KK + j];
    }
    #pragma unroll
    for (int p = 0; p < 16; ++p) S[ig*16+p][j] = acc[p];
    __syncthreads();
    for (int r = ig; r < 64; r += 4){
      float a = S[r][j];
      float m = wave_max(a);
      float e = __expf(a - m);
      attnRp[(((size_t)t2*CB + d)*KK + r)*KK + j] = e / wave_sum(e);
    }
  }
}

// ---------------- K7c: out_r PV ----------------
__global__ __launch_bounds__(256) void k7c(
    const float* __restrict__ attnRp, const float* __restrict__ vw, float* __restrict__ outa)
{
  int n = blockIdx.x % NWIN; int t2 = blockIdx.x / NWIN;
  __shared__ float vr[KK][CB];
  int t = threadIdx.x;
  for (int l = t; l < KK*CB; l += 256){
    int j = l >> 3, c = l & 7;
    vr[j][c] = vw[widx(t2, n, j, 24 + c)];
  }
  __syncthreads();
  int i = t & 63; int cg = t >> 6;
  int hw = n/NWS, ww = n%NWS; int kh = i>>3, kwd = i&7;
  int Y = (hw*8+kh+SSH)%IMG, X = (ww*8+kwd+SSH)%IMG;
  for (int c = cg*2; c < cg*2+2; ++c){
    const float* Pr = attnRp + (((size_t)t2*CB + c)*KK + i)*KK;
    float o = 0.f;
    for (int j = 0; j < KK; ++j) o += Pr[j]*vr[j][c];
    outa[((size_t)(96 + t2*CB + c)*IMG + Y)*IMG + X] = o;
  }
}

// ---------------- K8: channel means ----------------
__global__ __launch_bounds__(256) void k8_mean(const float* __restrict__ outa, float* __restrict__ meanb){
  int ch = blockIdx.x;
  const float4* p = (const float4*)(outa + (size_t)ch*HWP);
  float s = 0.f;
  for (int l = threadIdx.x; l < HWP/4; l += 256){
    float4 v = p[l]; s += v.x+v.y+v.z+v.w;
  }
  __shared__ float red[256];
  red[threadIdx.x] = s; __syncthreads();
  for (int k = 128; k > 0; k >>= 1){
    if (threadIdx.x < k) red[threadIdx.x] += red[threadIdx.x + k];
    __syncthreads();
  }
  if (threadIdx.x == 0) meanb[ch] = red[0] / (float)HWP;
}

// ---------------- K9a: out2z = (projw @ (outa*svec) + dwu) * zbuf ----------------
#define PADX 68
__global__ __launch_bounds__(256) void k9a(
    const float* __restrict__ outa, const float* __restrict__ meanb,
    const float* __restrict__ scaw, const float* __restrict__ scab,
    const float* __restrict__ projw, const float* __restrict__ dwu,
    const float* __restrict__ zbuf, float* __restrict__ out2z)
{
  __shared__ float WT[128][128];
  __shared__ float xsv[128][PADX];
  __shared__ float sv[128];
  int t = threadIdx.x;
  if (t < 128){
    float s = scab[t];
    const float* srow = scaw + (size_t)t*HD;
    for (int c = 0; c < HD; c += 4){
      float4 w = *(const float4*)&srow[c];
      float4 mm = *(const float4*)&meanb[c];
      s += w.x*mm.x + w.y*mm.y + w.z*mm.z + w.w*mm.w;
    }
    sv[t] = s;
  }
  for (int idx = t; idx < 4096; idx += 256){
    int o = idx & 127; int c4 = (idx >> 7) * 4;
    float4 w = *(const float4*)&projw[(size_t)o*HD + c4];
    WT[c4][o] = w.x; WT[c4+1][o] = w.y; WT[c4+2][o] = w.z; WT[c4+3][o] = w.w;
  }
  int px4 = (t & 15) * 4; int og8 = (t >> 4) * 8;
  for (int tile = 0; tile < 2; ++tile){
    int tid = blockIdx.x * 2 + tile;
    int y = tid / 3, x0 = (tid % 3) * 64;
    size_t sb = (size_t)y*IMG + x0;
    __syncthreads();
    for (int idx = t; idx < 2048; idx += 256){
      int c = idx >> 4; int p4 = (idx & 15) * 4;
      float4 v = *(const float4*)&outa[(size_t)c*HWP + sb + p4];
      float s = sv[c];
      xsv[c][p4] = v.x*s; xsv[c][p4+1] = v.y*s; xsv[c][p4+2] = v.z*s; xsv[c][p4+3] = v.w*s;
    }
    __syncthreads();
    float acc[8][4];
    #pragma unroll
    for (int a = 0; a < 8; ++a){ acc[a][0]=0.f; acc[a][1]=0.f; acc[a][2]=0.f; acc[a][3]=0.f; }
    for (int c = 0; c < 128; ++c){
      float4 xv = *(const float4*)&xsv[c][px4];
      float4 wA = *(const float4*)&WT[c][og8];
      float4 wB = *(const float4*)&WT[c][og8+4];
      float w8[8] = {wA.x,wA.y,wA.z,wA.w,wB.x,wB.y,wB.z,wB.w};
      #pragma unroll
      for (int a = 0; a < 8; ++a){
        acc[a][0] += w8[a]*xv.x; acc[a][1] += w8[a]*xv.y;
        acc[a][2] += w8[a]*xv.z; acc[a][3] += w8[a]*xv.w;
      }
    }
    #pragma unroll
    for (int oo = 0; oo < 8; ++oo){
      int o = og8 + oo;
      size_t off = (size_t)o*HWP + sb + px4;
      float4 d = *(const float4*)&dwu[off];
      float4 z = *(const float4*)&zbuf[off];
      float4 r;
      r.x = (acc[oo][0]+d.x)*z.x; r.y = (acc[oo][1]+d.y)*z.y;
      r.z = (acc[oo][2]+d.z)*z.z; r.w = (acc[oo][3]+d.w)*z.w;
      *(float4*)&out2z[off] = r;
    }
  }
}

// ---------------- K9b: dout = projow @ out2z ----------------
__global__ __launch_bounds__(256) void k9b(
    const float* __restrict__ out2z, const float* __restrict__ projow,
    float* __restrict__ dout, int bsel)
{
  __shared__ float WT2[128][64];
  __shared__ float xsv[128][PADX];
  int t = threadIdx.x;
  for (int idx = t; idx < 2048; idx += 256){
    int o = idx & 63; int c4 = (idx >> 6) * 4;
    float4 w = *(const float4*)&projow[(size_t)o*HD + c4];
    WT2[c4][o] = w.x; WT2[c4+1][o] = w.y; WT2[c4+2][o] = w.z; WT2[c4+3][o] = w.w;
  }
  int px4 = (t & 15) * 4; int og4 = (t >> 4) * 4;
  for (int tile = 0; tile < 2; ++tile){
    int tid = blockIdx.x * 2 + tile;
    int y = tid / 3, x0 = (tid % 3) * 64;
    size_t sb = (size_t)y*IMG + x0;
    __syncthreads();
    for (int idx = t; idx < 2048; idx += 256){
      int c = idx >> 4; int p4 = (idx & 15) * 4;
      float4 v = *(const float4*)&out2z[(size_t)c*HWP + sb + p4];
      xsv[c][p4] = v.x; xsv[c][p4+1] = v.y; xsv[c][p4+2] = v.z; xsv[c][p4+3] = v.w;
    }
    __syncthreads();
    float acc[4][4];
    #pragma unroll
    for (int a = 0; a < 4; ++a){ acc[a][0]=0.f; acc[a][1]=0.f; acc[a][2]=0.f; acc[a][3]=0.f; }
    for (int c = 0; c < 128; ++c){
      float4 xv = *(const float4*)&xsv[c][px4];
      float4 w4 = *(const float4*)&WT2[c][og4];
      float w4a[4] = {w4.x,w4.y,w4.z,w4.w};
      #pragma unroll
      for (int a = 0; a < 4; ++a){
        acc[a][0] += w4a[a]*xv.x; acc[a][1] += w4a[a]*xv.y;
        acc[a][2] += w4a[a]*xv.z; acc[a][3] += w4a[a]*xv.w;
      }
    }
    #pragma unroll
    for (int oo = 0; oo < 4; ++oo){
      int o = og4 + oo;
      float4 r; r.x = acc[oo][0]; r.y = acc[oo][1]; r.z = acc[oo][2]; r.w = acc[oo][3];
      *(float4*)&dout[(size_t)(bsel*CIN + o)*HWP + sb + px4] = r;
    }
  }
}

// ---------------- launch ----------------
extern "C" void kernel_launch(void* const* d_in, const int* in_sizes, int n_in,
                              void* d_out, int out_size, void* d_ws, size_t ws_size,
                              hipStream_t stream)
{
  const float* x     = (const float*)d_in[0];
  const float* wquz  = (const float*)d_in[1];
  const float* wkv   = (const float*)d_in[2];
  const float* temp  = (const float*)d_in[3];
  const float* rtalk = (const float*)d_in[4];
  const float* gtalk = (const float*)d_in[5];
  const float* btw   = (const float*)d_in[6];
  const float* ltw   = (const float*)d_in[7];
  const float* dww   = (const float*)d_in[8];
  const float* projw = (const float*)d_in[9];
  const float* projow= (const float*)d_in[10];
  const float* scaw  = (const float*)d_in[11];
  const float* scab  = (const float*)d_in[12];
  float* dout = (float*)d_out;

  float* ws = (float*)d_ws;
  float* qw    = ws;                  // NQK16
  float* kw    = qw + NQK16;          // NQK16
  float* vw    = kw + NQK16;          // NV32
  float* qg    = vw + NV32;           // NGR
  float* kg    = qg + NGR;            // NGR
  float* qr    = kg + NGR;            // NGR
  float* kr    = qr + NGR;            // NGR
  float* u     = kr + NGR;            // NSP
  float* zbuf  = u + NSP;             // NSP
  float* outa  = zbuf + NSP;          // NSP
  float* attnBf= outa + NSP;          // fp16 attnB region: NATTNB halves == NSP floats
  __half* attnBh = (__half*)attnBf;
  float* attnL = attnBf + NSP;        // NATTNL
  float* attnG = attnL + NATTNL;      // NATTNG
  float* attnGp= attnG + NATTNG;      // NATTNG
  float* part  = attnGp + NATTNG;     // NPART
  float* attnR = part + NPART;        // NATTNR
  float* attnRp= attnR + NATTNR;      // NATTNR
  float* invqr = attnRp + NATTNR;     // 2048
  float* invkr = invqr + 2048;        // 2048
  float* meanb = invkr + 2048;        // 128
  // Aliases (lifetime-disjoint):
  float* dwu   = qw;                  // qw/kw dead after kA; 2*NQK16 == NSP
  float* out2z = attnBf;              // attnB dead after kB; region == NSP floats

  for (int b = 0; b < BB; ++b){
    k1_proj<<<IMG*12, 256, 0, stream>>>(x, wquz, wkv, qw, kw, vw, qg, kg, qr, kr, u, zbuf, b);

    kA<<<1696, 256, 0, stream>>>(qw, kw, qg, kg, qr, kr, temp,
                                 attnBh, attnL, attnG, part, invqr, invkr);

    kB<<<16512, 256, 0, stream>>>(attnBh, btw, vw, outa, attnL, ltw,
                                  attnG, gtalk, attnGp, part, invqr, invkr, temp, attnR,
                                  u, dww, dwu);

    kC<<<2336, 256, 0, stream>>>(attnGp, vw, outa, attnR, rtalk, attnRp);

    k7c<<<NH*NWIN, 256, 0, stream>>>(attnRp, vw, outa);

    k8_mean<<<HD, 256, 0, stream>>>(outa, meanb);

    k9a<<<288, 256, 0, stream>>>(outa, meanb, scaw, scab, projw, dwu, zbuf, out2z);
    k9b<<<288, 256, 0, stream>>>(out2z, projow, dout, b);
  }
}